// Round 1
// baseline (3112.272 us; speedup 1.0000x reference)
//
#include <hip/hip_runtime.h>
#include <hip/hip_bf16.h>
#include <math.h>

#define N_NODES 50000
#define N_EDGES 1600000
#define NFEAT   512
#define NHID    128
#define NCLASS  40

// ---------------- GEMM1: S1[M=50000,128] = x[M,512] @ W1[512,128] ----------------
// 64x128 block tile, BK=32, 256 threads, 8x4 per-thread microtile.
__global__ __launch_bounds__(256) void gemm1_kernel(const float* __restrict__ A,
                                                    const float* __restrict__ B,
                                                    float* __restrict__ C) {
  __shared__ float As[64][32];
  __shared__ float Bs[32][128];
  const int tid = threadIdx.x;
  const int tx = tid & 31;   // N: 32 chunks of 4
  const int ty = tid >> 5;   // M: 8 chunks of 8
  const int rowBase = blockIdx.x * 64;

  float acc[8][4];
#pragma unroll
  for (int i = 0; i < 8; ++i)
#pragma unroll
    for (int j = 0; j < 4; ++j) acc[i][j] = 0.f;

  for (int k0 = 0; k0 < NFEAT; k0 += 32) {
    // stage A tile (64x32): 2 float4 per thread, rows guarded
    {
      const int r = tid >> 3;
      const int c = (tid & 7) << 2;
#pragma unroll
      for (int h = 0; h < 2; ++h) {
        const int rr = r + h * 32;
        const int grow = rowBase + rr;
        float4 v = make_float4(0.f, 0.f, 0.f, 0.f);
        if (grow < N_NODES) v = *(const float4*)&A[(size_t)grow * NFEAT + k0 + c];
        *(float4*)&As[rr][c] = v;
      }
    }
    // stage B tile (32x128): 4 float4 per thread
    {
      const int r = tid >> 5;
      const int c = (tid & 31) << 2;
#pragma unroll
      for (int h = 0; h < 4; ++h) {
        const int rr = r + h * 8;
        *(float4*)&Bs[rr][c] = *(const float4*)&B[(size_t)(k0 + rr) * NHID + c];
      }
    }
    __syncthreads();
#pragma unroll 8
    for (int kk = 0; kk < 32; ++kk) {
      float b[4];
      *(float4*)b = *(const float4*)&Bs[kk][tx << 2];
#pragma unroll
      for (int i = 0; i < 8; ++i) {
        const float a = As[(ty << 3) + i][kk];  // 2-way broadcast read: free
#pragma unroll
        for (int j = 0; j < 4; ++j) acc[i][j] = fmaf(a, b[j], acc[i][j]);
      }
    }
    __syncthreads();
  }
#pragma unroll
  for (int i = 0; i < 8; ++i) {
    const int grow = rowBase + (ty << 3) + i;
    if (grow < N_NODES)
      *(float4*)&C[(size_t)grow * NHID + (tx << 2)] = *(const float4*)&acc[i][0];
  }
}

// ---------------- bias init: Agg[n][c] = b[c] ----------------
template <int NC>
__global__ __launch_bounds__(256) void init_bias_kernel(float* __restrict__ Agg,
                                                        const float* __restrict__ b,
                                                        int total) {
  int i = blockIdx.x * 256 + threadIdx.x;
  if (i < total) Agg[i] = b[i % NC];
}

// ---------------- scatter1: Agg1[dst] += w * S1[src], 128 feats ----------------
// one thread per (edge, float4-chunk): 32 chunks/edge
__global__ __launch_bounds__(256) void scatter1_kernel(const int* __restrict__ ei,
                                                       const float* __restrict__ ew,
                                                       const float* __restrict__ S,
                                                       float* __restrict__ Agg) {
  const unsigned tid = blockIdx.x * 256u + threadIdx.x;
  const unsigned e = tid >> 5;
  if (e >= N_EDGES) return;
  const int c = (tid & 31) << 2;
  const int src = ei[e];
  const int dst = ei[N_EDGES + e];
  const float w = ew[e];
  float4 v = *(const float4*)&S[(size_t)src * NHID + c];
  float* out = &Agg[(size_t)dst * NHID + c];
  atomicAdd(out + 0, w * v.x);
  atomicAdd(out + 1, w * v.y);
  atomicAdd(out + 2, w * v.z);
  atomicAdd(out + 3, w * v.w);
}

// ---------------- GEMM2: S2[M,40] = relu(Agg1)[M,128] @ W2[128,40] ----------------
// 320 threads = 8 rows x 40 cols per block; W2 staged in LDS.
__global__ __launch_bounds__(320) void gemm2_kernel(const float* __restrict__ Agg1,
                                                    const float* __restrict__ W2,
                                                    float* __restrict__ S2) {
  __shared__ float Bs[NHID * NCLASS];
  for (int i = threadIdx.x; i < NHID * NCLASS; i += 320) Bs[i] = W2[i];
  __syncthreads();
  const int row = blockIdx.x * 8 + threadIdx.x / NCLASS;
  const int col = threadIdx.x % NCLASS;
  if (row >= N_NODES) return;
  const float* __restrict__ arow = &Agg1[(size_t)row * NHID];
  float acc = 0.f;
#pragma unroll 8
  for (int k = 0; k < NHID; ++k) {
    const float a = fmaxf(arow[k], 0.f);  // fused relu
    acc = fmaf(a, Bs[k * NCLASS + col], acc);
  }
  S2[(size_t)row * NCLASS + col] = acc;
}

// ---------------- scatter2: Agg2[dst] += w * S2[src], 40 feats ----------------
__global__ __launch_bounds__(256) void scatter2_kernel(const int* __restrict__ ei,
                                                       const float* __restrict__ ew,
                                                       const float* __restrict__ S,
                                                       float* __restrict__ Agg) {
  const unsigned tid = blockIdx.x * 256u + threadIdx.x;
  const unsigned e = tid / 40u;
  if (e >= N_EDGES) return;
  const int c = tid % 40u;
  const int src = ei[e];
  const int dst = ei[N_EDGES + e];
  const float w = ew[e];
  atomicAdd(&Agg[(size_t)dst * NCLASS + c], w * S[(size_t)src * NCLASS + c]);
}

// ---------------- log_softmax over 40 classes, one wave per row ----------------
__global__ __launch_bounds__(256) void lsm_kernel(const float* __restrict__ Agg2,
                                                  float* __restrict__ out) {
  const int wave = threadIdx.x >> 6;
  const int lane = threadIdx.x & 63;
  const int row = blockIdx.x * 4 + wave;
  if (row >= N_NODES) return;
  const float* __restrict__ r = &Agg2[(size_t)row * NCLASS];
  const float v = (lane < NCLASS) ? r[lane] : -3.4e38f;
  float m = v;
#pragma unroll
  for (int off = 32; off; off >>= 1) m = fmaxf(m, __shfl_xor(m, off));
  float ex = (lane < NCLASS) ? __expf(v - m) : 0.f;
  float s = ex;
#pragma unroll
  for (int off = 32; off; off >>= 1) s += __shfl_xor(s, off);
  const float lse = m + __logf(s);
  if (lane < NCLASS) out[(size_t)row * NCLASS + lane] = v - lse;
}

extern "C" void kernel_launch(void* const* d_in, const int* in_sizes, int n_in,
                              void* d_out, int out_size, void* d_ws, size_t ws_size,
                              hipStream_t stream) {
  const float* x   = (const float*)d_in[0];
  // d_in[1] = target_feats (unused)
  const int*   ei1 = (const int*)d_in[2];
  const float* ew1 = (const float*)d_in[3];
  const int*   ei2 = (const int*)d_in[4];
  const float* ew2 = (const float*)d_in[5];
  const float* W1  = (const float*)d_in[6];
  const float* b1  = (const float*)d_in[7];
  const float* W2  = (const float*)d_in[8];
  const float* b2  = (const float*)d_in[9];
  float* out = (float*)d_out;

  float* S1   = (float*)d_ws;                 // 50000*128
  float* Agg1 = S1 + (size_t)N_NODES * NHID;  // 50000*128
  float* S2   = Agg1 + (size_t)N_NODES * NHID;   // 50000*40
  float* Agg2 = S2 + (size_t)N_NODES * NCLASS;   // 50000*40

  // Layer 1
  gemm1_kernel<<<(N_NODES + 63) / 64, 256, 0, stream>>>(x, W1, S1);
  {
    const int total = N_NODES * NHID;
    init_bias_kernel<NHID><<<(total + 255) / 256, 256, 0, stream>>>(Agg1, b1, total);
  }
  {
    const unsigned total = (unsigned)N_EDGES * 32u;
    scatter1_kernel<<<(total + 255) / 256, 256, 0, stream>>>(ei1, ew1, S1, Agg1);
  }

  // Layer 2 (relu fused into gemm2 A-load)
  gemm2_kernel<<<(N_NODES + 7) / 8, 320, 0, stream>>>(Agg1, W2, S2);
  {
    const int total = N_NODES * NCLASS;
    init_bias_kernel<NCLASS><<<(total + 255) / 256, 256, 0, stream>>>(Agg2, b2, total);
  }
  {
    const unsigned total = (unsigned)N_EDGES * 40u;
    scatter2_kernel<<<(total + 255) / 256, 256, 0, stream>>>(ei2, ew2, S2, Agg2);
  }

  // log_softmax
  lsm_kernel<<<(N_NODES + 3) / 4, 256, 0, stream>>>(Agg2, out);
}

// Round 2
// 874.460 us; speedup vs baseline: 3.5591x; 3.5591x over previous
//
#include <hip/hip_runtime.h>
#include <hip/hip_bf16.h>
#include <math.h>

#define N_NODES 50000
#define N_EDGES 1600000
#define NFEAT   512
#define NHID    128
#define NCLASS  40

#define SCAN_CHUNK 2048
#define SCAN_NBLK ((N_NODES + SCAN_CHUNK - 1) / SCAN_CHUNK)  // 25

// ---------------- GEMM1: S1[M=50000,128] = x[M,512] @ W1[512,128] ----------------
__global__ __launch_bounds__(256) void gemm1_kernel(const float* __restrict__ A,
                                                    const float* __restrict__ B,
                                                    float* __restrict__ C) {
  __shared__ float As[64][32];
  __shared__ float Bs[32][128];
  const int tid = threadIdx.x;
  const int tx = tid & 31;   // N: 32 chunks of 4
  const int ty = tid >> 5;   // M: 8 chunks of 8
  const int rowBase = blockIdx.x * 64;

  float acc[8][4];
#pragma unroll
  for (int i = 0; i < 8; ++i)
#pragma unroll
    for (int j = 0; j < 4; ++j) acc[i][j] = 0.f;

  for (int k0 = 0; k0 < NFEAT; k0 += 32) {
    {
      const int r = tid >> 3;
      const int c = (tid & 7) << 2;
#pragma unroll
      for (int h = 0; h < 2; ++h) {
        const int rr = r + h * 32;
        const int grow = rowBase + rr;
        float4 v = make_float4(0.f, 0.f, 0.f, 0.f);
        if (grow < N_NODES) v = *(const float4*)&A[(size_t)grow * NFEAT + k0 + c];
        *(float4*)&As[rr][c] = v;
      }
    }
    {
      const int r = tid >> 5;
      const int c = (tid & 31) << 2;
#pragma unroll
      for (int h = 0; h < 4; ++h) {
        const int rr = r + h * 8;
        *(float4*)&Bs[rr][c] = *(const float4*)&B[(size_t)(k0 + rr) * NHID + c];
      }
    }
    __syncthreads();
#pragma unroll 8
    for (int kk = 0; kk < 32; ++kk) {
      float b[4];
      *(float4*)b = *(const float4*)&Bs[kk][tx << 2];
#pragma unroll
      for (int i = 0; i < 8; ++i) {
        const float a = As[(ty << 3) + i][kk];
#pragma unroll
        for (int j = 0; j < 4; ++j) acc[i][j] = fmaf(a, b[j], acc[i][j]);
      }
    }
    __syncthreads();
  }
#pragma unroll
  for (int i = 0; i < 8; ++i) {
    const int grow = rowBase + (ty << 3) + i;
    if (grow < N_NODES)
      *(float4*)&C[(size_t)grow * NHID + (tx << 2)] = *(const float4*)&acc[i][0];
  }
}

// ---------------- CSR build: zero, histogram, 2-level scan, fill ----------------
__global__ __launch_bounds__(256) void zero_i32_kernel(int* __restrict__ p, int n) {
  int i = blockIdx.x * 256 + threadIdx.x;
  if (i < n) p[i] = 0;
}

__global__ __launch_bounds__(256) void hist_kernel(const int* __restrict__ ei,
                                                   int* __restrict__ counts) {
  int e = blockIdx.x * 256 + threadIdx.x;
  if (e < N_EDGES) atomicAdd(&counts[ei[N_EDGES + e]], 1);
}

// block scans SCAN_CHUNK=2048 elements (8/thread), writes exclusive prefix + block total
__global__ __launch_bounds__(256) void scan1_kernel(const int* __restrict__ counts,
                                                    int* __restrict__ row_ptr,
                                                    int* __restrict__ partials) {
  __shared__ int sdata[256];
  const int tid = threadIdx.x;
  const int base = blockIdx.x * SCAN_CHUNK + tid * 8;
  int local[8];
  int sum = 0;
#pragma unroll
  for (int j = 0; j < 8; ++j) {
    const int idx = base + j;
    const int v = (idx < N_NODES) ? counts[idx] : 0;
    local[j] = sum;  // exclusive within thread
    sum += v;
  }
  sdata[tid] = sum;
  __syncthreads();
  for (int d = 1; d < 256; d <<= 1) {
    const int a = (tid >= d) ? sdata[tid - d] : 0;
    __syncthreads();
    sdata[tid] += a;
    __syncthreads();
  }
  const int excl = sdata[tid] - sum;
#pragma unroll
  for (int j = 0; j < 8; ++j) {
    const int idx = base + j;
    if (idx < N_NODES) row_ptr[idx] = local[j] + excl;
  }
  if (tid == 255) partials[blockIdx.x] = sdata[255];
}

__global__ void scan2_kernel(int* __restrict__ partials) {
  if (threadIdx.x == 0 && blockIdx.x == 0) {
    int run = 0;
    for (int b = 0; b < SCAN_NBLK; ++b) {
      const int t = partials[b];
      partials[b] = run;
      run += t;
    }
  }
}

// add block offsets; also init cursor = row start; set row_ptr[N] = E
__global__ __launch_bounds__(256) void scan3_kernel(int* __restrict__ row_ptr,
                                                    int* __restrict__ cursor,
                                                    const int* __restrict__ partials) {
  int i = blockIdx.x * 256 + threadIdx.x;
  if (i < N_NODES) {
    const int v = row_ptr[i] + partials[i / SCAN_CHUNK];
    row_ptr[i] = v;
    cursor[i] = v;
  } else if (i == N_NODES) {
    row_ptr[N_NODES] = N_EDGES;
  }
}

__global__ __launch_bounds__(256) void fill_kernel(const int* __restrict__ ei,
                                                   const float* __restrict__ ew,
                                                   int* __restrict__ cursor,
                                                   int* __restrict__ csr_src,
                                                   float* __restrict__ csr_w) {
  int e = blockIdx.x * 256 + threadIdx.x;
  if (e >= N_EDGES) return;
  const int dst = ei[N_EDGES + e];
  const int pos = atomicAdd(&cursor[dst], 1);
  csr_src[pos] = ei[e];
  csr_w[pos] = ew[e];
}

// ---------------- agg1 (pull): H1[n] = relu(b1 + sum_e w_e * S1[src_e]), 128 feats ----------------
// one wave per node; lane handles float2 (128 = 64*2), fully coalesced row reads
__global__ __launch_bounds__(256) void agg1_kernel(const int* __restrict__ row_ptr,
                                                   const int* __restrict__ csr_src,
                                                   const float* __restrict__ csr_w,
                                                   const float* __restrict__ S1,
                                                   const float* __restrict__ b1,
                                                   float* __restrict__ H1) {
  const int wave = threadIdx.x >> 6;
  const int lane = threadIdx.x & 63;
  const int n = blockIdx.x * 4 + wave;
  if (n >= N_NODES) return;
  const int c = lane << 1;
  float2 acc = *(const float2*)&b1[c];
  const int beg = row_ptr[n];
  const int end = row_ptr[n + 1];
  for (int e = beg; e < end; ++e) {
    const int src = csr_src[e];
    const float w = csr_w[e];
    const float2 v = *(const float2*)&S1[(size_t)src * NHID + c];
    acc.x = fmaf(w, v.x, acc.x);
    acc.y = fmaf(w, v.y, acc.y);
  }
  acc.x = fmaxf(acc.x, 0.f);
  acc.y = fmaxf(acc.y, 0.f);
  *(float2*)&H1[(size_t)n * NHID + c] = acc;
}

// ---------------- GEMM2: S2[M,40] = H1[M,128] @ W2[128,40] (H1 already relu'd) ----------------
__global__ __launch_bounds__(320) void gemm2_kernel(const float* __restrict__ H1,
                                                    const float* __restrict__ W2,
                                                    float* __restrict__ S2) {
  __shared__ float Bs[NHID * NCLASS];
  for (int i = threadIdx.x; i < NHID * NCLASS; i += 320) Bs[i] = W2[i];
  __syncthreads();
  const int row = blockIdx.x * 8 + threadIdx.x / NCLASS;
  const int col = threadIdx.x % NCLASS;
  if (row >= N_NODES) return;
  const float* __restrict__ arow = &H1[(size_t)row * NHID];
  float acc = 0.f;
#pragma unroll 8
  for (int k = 0; k < NHID; ++k) acc = fmaf(arow[k], Bs[k * NCLASS + col], acc);
  S2[(size_t)row * NCLASS + col] = acc;
}

// ---------------- agg2 + bias + log_softmax fused: out[n] = lsm(b2 + sum w*S2[src]) ----------------
__global__ __launch_bounds__(256) void agg2_lsm_kernel(const int* __restrict__ row_ptr,
                                                       const int* __restrict__ csr_src,
                                                       const float* __restrict__ csr_w,
                                                       const float* __restrict__ S2,
                                                       const float* __restrict__ b2,
                                                       float* __restrict__ out) {
  const int wave = threadIdx.x >> 6;
  const int lane = threadIdx.x & 63;
  const int n = blockIdx.x * 4 + wave;
  if (n >= N_NODES) return;
  const bool act = lane < NCLASS;
  float acc = act ? b2[lane] : 0.f;
  const int beg = row_ptr[n];
  const int end = row_ptr[n + 1];
  for (int e = beg; e < end; ++e) {
    const int src = csr_src[e];
    const float w = csr_w[e];
    if (act) acc = fmaf(w, S2[(size_t)src * NCLASS + lane], acc);
  }
  const float v = act ? acc : -3.4e38f;
  float m = v;
#pragma unroll
  for (int off = 32; off; off >>= 1) m = fmaxf(m, __shfl_xor(m, off));
  float ex = act ? __expf(v - m) : 0.f;
  float s = ex;
#pragma unroll
  for (int off = 32; off; off >>= 1) s += __shfl_xor(s, off);
  const float lse = m + __logf(s);
  if (act) out[(size_t)n * NCLASS + lane] = v - lse;
}

// ---------------- launch ----------------
static void build_csr(const int* ei, const float* ew, int* row_ptr, int* cursor,
                      int* partials, int* csr_src, float* csr_w, hipStream_t stream) {
  zero_i32_kernel<<<(N_NODES + 255) / 256, 256, 0, stream>>>(cursor, N_NODES);
  hist_kernel<<<(N_EDGES + 255) / 256, 256, 0, stream>>>(ei, cursor);
  scan1_kernel<<<SCAN_NBLK, 256, 0, stream>>>(cursor, row_ptr, partials);
  scan2_kernel<<<1, 64, 0, stream>>>(partials);
  scan3_kernel<<<(N_NODES + 1 + 255) / 256, 256, 0, stream>>>(row_ptr, cursor, partials);
  fill_kernel<<<(N_EDGES + 255) / 256, 256, 0, stream>>>(ei, ew, cursor, csr_src, csr_w);
}

extern "C" void kernel_launch(void* const* d_in, const int* in_sizes, int n_in,
                              void* d_out, int out_size, void* d_ws, size_t ws_size,
                              hipStream_t stream) {
  const float* x   = (const float*)d_in[0];
  const int*   ei1 = (const int*)d_in[2];
  const float* ew1 = (const float*)d_in[3];
  const int*   ei2 = (const int*)d_in[4];
  const float* ew2 = (const float*)d_in[5];
  const float* W1  = (const float*)d_in[6];
  const float* b1  = (const float*)d_in[7];
  const float* W2  = (const float*)d_in[8];
  const float* b2  = (const float*)d_in[9];
  float* out = (float*)d_out;

  // workspace layout (all 4-byte elems); CSR arrays time-shared between graphs
  float* S1      = (float*)d_ws;                       // 6.4M
  float* H1      = S1 + (size_t)N_NODES * NHID;        // 6.4M (relu'd)
  float* S2      = H1 + (size_t)N_NODES * NHID;        // 2.0M
  int*   row_ptr1 = (int*)(S2 + (size_t)N_NODES * NCLASS);  // 50001
  int*   cursor1  = row_ptr1 + (N_NODES + 1);               // 50000
  int*   row_ptr2 = cursor1 + N_NODES;                      // 50001
  int*   cursor2  = row_ptr2 + (N_NODES + 1);               // 50000
  int*   partials = cursor2 + N_NODES;                      // 64
  int*   csr_src  = partials + 64;                          // 1.6M
  float* csr_w    = (float*)(csr_src + N_EDGES);            // 1.6M
  // total ~72.6 MB

  // layer 1
  build_csr(ei1, ew1, row_ptr1, cursor1, partials, csr_src, csr_w, stream);
  gemm1_kernel<<<(N_NODES + 63) / 64, 256, 0, stream>>>(x, W1, S1);
  agg1_kernel<<<(N_NODES + 3) / 4, 256, 0, stream>>>(row_ptr1, csr_src, csr_w, S1, b1, H1);

  // layer 2 (reuses csr_src/csr_w after agg1 is done; stream-ordered)
  build_csr(ei2, ew2, row_ptr2, cursor2, partials, csr_src, csr_w, stream);
  gemm2_kernel<<<(N_NODES + 7) / 8, 320, 0, stream>>>(H1, W2, S2);
  agg2_lsm_kernel<<<(N_NODES + 3) / 4, 256, 0, stream>>>(row_ptr2, csr_src, csr_w, S2, b2, out);
}

// Round 3
// 650.032 us; speedup vs baseline: 4.7879x; 1.3453x over previous
//
#include <hip/hip_runtime.h>
#include <hip/hip_bf16.h>
#include <math.h>

#define N_NODES 50000
#define N_TOT   100000          // both graphs concatenated
#define N_EDGES 1600000
#define E_TOT   3200000
#define NFEAT   512
#define NHID    128
#define NCLASS  40

#define SCAN_CHUNK 2048
#define SCAN_NBLK ((N_TOT + SCAN_CHUNK - 1) / SCAN_CHUNK)  // 49

__device__ __forceinline__ float bf_lo(unsigned u) { return __uint_as_float(u << 16); }
__device__ __forceinline__ float bf_hi(unsigned u) { return __uint_as_float(u & 0xFFFF0000u); }
__device__ __forceinline__ unsigned short f2bf(float f) {
  __hip_bfloat16 h = __float2bfloat16(f);
  return *(unsigned short*)&h;
}

// ---------------- GEMM1: S1b[M=50000,128](bf16) = x[M,512] @ W1[512,128] ----------------
__global__ __launch_bounds__(256) void gemm1_kernel(const float* __restrict__ A,
                                                    const float* __restrict__ B,
                                                    unsigned short* __restrict__ Cb) {
  __shared__ float As[64][32];
  __shared__ float Bs[32][128];
  const int tid = threadIdx.x;
  const int tx = tid & 31;   // N: 32 chunks of 4
  const int ty = tid >> 5;   // M: 8 chunks of 8
  const int rowBase = blockIdx.x * 64;

  float acc[8][4];
#pragma unroll
  for (int i = 0; i < 8; ++i)
#pragma unroll
    for (int j = 0; j < 4; ++j) acc[i][j] = 0.f;

  for (int k0 = 0; k0 < NFEAT; k0 += 32) {
    {
      const int r = tid >> 3;
      const int c = (tid & 7) << 2;
#pragma unroll
      for (int h = 0; h < 2; ++h) {
        const int rr = r + h * 32;
        const int grow = rowBase + rr;
        float4 v = make_float4(0.f, 0.f, 0.f, 0.f);
        if (grow < N_NODES) v = *(const float4*)&A[(size_t)grow * NFEAT + k0 + c];
        *(float4*)&As[rr][c] = v;
      }
    }
    {
      const int r = tid >> 5;
      const int c = (tid & 31) << 2;
#pragma unroll
      for (int h = 0; h < 4; ++h) {
        const int rr = r + h * 8;
        *(float4*)&Bs[rr][c] = *(const float4*)&B[(size_t)(k0 + rr) * NHID + c];
      }
    }
    __syncthreads();
#pragma unroll 8
    for (int kk = 0; kk < 32; ++kk) {
      float b[4];
      *(float4*)b = *(const float4*)&Bs[kk][tx << 2];
#pragma unroll
      for (int i = 0; i < 8; ++i) {
        const float a = As[(ty << 3) + i][kk];
#pragma unroll
        for (int j = 0; j < 4; ++j) acc[i][j] = fmaf(a, b[j], acc[i][j]);
      }
    }
    __syncthreads();
  }
#pragma unroll
  for (int i = 0; i < 8; ++i) {
    const int grow = rowBase + (ty << 3) + i;
    if (grow < N_NODES) {
      ushort4 o;
      o.x = f2bf(acc[i][0]); o.y = f2bf(acc[i][1]);
      o.z = f2bf(acc[i][2]); o.w = f2bf(acc[i][3]);
      *(ushort4*)&Cb[(size_t)grow * NHID + (tx << 2)] = o;
    }
  }
}

// ---------------- combined CSR build over both graphs ----------------
__global__ __launch_bounds__(256) void zero_i32_kernel(int* __restrict__ p, int n) {
  int i = blockIdx.x * 256 + threadIdx.x;
  if (i < n) p[i] = 0;
}

__global__ __launch_bounds__(256) void hist_kernel(const int* __restrict__ ei1,
                                                   const int* __restrict__ ei2,
                                                   int* __restrict__ counts) {
  int e = blockIdx.x * 256 + threadIdx.x;
  if (e >= E_TOT) return;
  const int g = (e >= N_EDGES);
  const int le = e - (g ? N_EDGES : 0);
  const int* ei = g ? ei2 : ei1;
  const int dst = ei[N_EDGES + le] + g * N_NODES;
  atomicAdd(&counts[dst], 1);
}

__global__ __launch_bounds__(256) void scan1_kernel(const int* __restrict__ counts,
                                                    int* __restrict__ row_ptr,
                                                    int* __restrict__ partials) {
  __shared__ int sdata[256];
  const int tid = threadIdx.x;
  const int base = blockIdx.x * SCAN_CHUNK + tid * 8;
  int local[8];
  int sum = 0;
#pragma unroll
  for (int j = 0; j < 8; ++j) {
    const int idx = base + j;
    const int v = (idx < N_TOT) ? counts[idx] : 0;
    local[j] = sum;
    sum += v;
  }
  sdata[tid] = sum;
  __syncthreads();
  for (int d = 1; d < 256; d <<= 1) {
    const int a = (tid >= d) ? sdata[tid - d] : 0;
    __syncthreads();
    sdata[tid] += a;
    __syncthreads();
  }
  const int excl = sdata[tid] - sum;
#pragma unroll
  for (int j = 0; j < 8; ++j) {
    const int idx = base + j;
    if (idx < N_TOT) row_ptr[idx] = local[j] + excl;
  }
  if (tid == 255) partials[blockIdx.x] = sdata[255];
}

__global__ void scan2_kernel(int* __restrict__ partials) {
  if (threadIdx.x == 0 && blockIdx.x == 0) {
    int run = 0;
    for (int b = 0; b < SCAN_NBLK; ++b) {
      const int t = partials[b];
      partials[b] = run;
      run += t;
    }
  }
}

__global__ __launch_bounds__(256) void scan3_kernel(int* __restrict__ row_ptr,
                                                    int* __restrict__ cursor,
                                                    const int* __restrict__ partials) {
  int i = blockIdx.x * 256 + threadIdx.x;
  if (i < N_TOT) {
    const int v = row_ptr[i] + partials[i / SCAN_CHUNK];
    row_ptr[i] = v;
    cursor[i] = v;
  } else if (i == N_TOT) {
    row_ptr[N_TOT] = E_TOT;
  }
}

__global__ __launch_bounds__(256) void fill_kernel(const int* __restrict__ ei1,
                                                   const float* __restrict__ ew1,
                                                   const int* __restrict__ ei2,
                                                   const float* __restrict__ ew2,
                                                   int* __restrict__ cursor,
                                                   int2* __restrict__ ent) {
  int e = blockIdx.x * 256 + threadIdx.x;
  if (e >= E_TOT) return;
  const int g = (e >= N_EDGES);
  const int le = e - (g ? N_EDGES : 0);
  const int* ei = g ? ei2 : ei1;
  const float* ew = g ? ew2 : ew1;
  const int src = ei[le];
  const int dst = ei[N_EDGES + le] + g * N_NODES;
  const int pos = atomicAdd(&cursor[dst], 1);
  ent[pos] = make_int2(src, __float_as_int(ew[le]));
}

// ---------------- agg1 (pull, bf16 gather): H1 = relu(b1 + sum w*S1b[src]) ----------------
__global__ __launch_bounds__(256) void agg1_kernel(const int* __restrict__ rp,
                                                   const int2* __restrict__ ent,
                                                   const unsigned short* __restrict__ S1b,
                                                   const float* __restrict__ b1,
                                                   float* __restrict__ H1) {
  const int wave = threadIdx.x >> 6;
  const int lane = threadIdx.x & 63;
  const int n = blockIdx.x * 4 + wave;
  if (n >= N_NODES) return;
  const int c = lane << 1;
  float2 acc = *(const float2*)&b1[c];
  int e = rp[n];
  const int end = rp[n + 1];
  for (; e + 4 <= end; e += 4) {
    const int2 q0 = ent[e], q1 = ent[e + 1], q2 = ent[e + 2], q3 = ent[e + 3];
    const unsigned u0 = *(const unsigned*)&S1b[(size_t)q0.x * NHID + c];
    const unsigned u1 = *(const unsigned*)&S1b[(size_t)q1.x * NHID + c];
    const unsigned u2 = *(const unsigned*)&S1b[(size_t)q2.x * NHID + c];
    const unsigned u3 = *(const unsigned*)&S1b[(size_t)q3.x * NHID + c];
    const float w0 = __int_as_float(q0.y), w1 = __int_as_float(q1.y);
    const float w2 = __int_as_float(q2.y), w3 = __int_as_float(q3.y);
    acc.x = fmaf(w0, bf_lo(u0), acc.x); acc.y = fmaf(w0, bf_hi(u0), acc.y);
    acc.x = fmaf(w1, bf_lo(u1), acc.x); acc.y = fmaf(w1, bf_hi(u1), acc.y);
    acc.x = fmaf(w2, bf_lo(u2), acc.x); acc.y = fmaf(w2, bf_hi(u2), acc.y);
    acc.x = fmaf(w3, bf_lo(u3), acc.x); acc.y = fmaf(w3, bf_hi(u3), acc.y);
  }
  for (; e < end; ++e) {
    const int2 q = ent[e];
    const unsigned u = *(const unsigned*)&S1b[(size_t)q.x * NHID + c];
    const float w = __int_as_float(q.y);
    acc.x = fmaf(w, bf_lo(u), acc.x);
    acc.y = fmaf(w, bf_hi(u), acc.y);
  }
  acc.x = fmaxf(acc.x, 0.f);
  acc.y = fmaxf(acc.y, 0.f);
  *(float2*)&H1[(size_t)n * NHID + c] = acc;
}

// ---------------- GEMM2: S2b[M,40](bf16) = H1[M,128] @ W2[128,40] ----------------
__global__ __launch_bounds__(320) void gemm2_kernel(const float* __restrict__ H1,
                                                    const float* __restrict__ W2,
                                                    unsigned short* __restrict__ S2b) {
  __shared__ float Bs[NHID * NCLASS];
  for (int i = threadIdx.x; i < NHID * NCLASS; i += 320) Bs[i] = W2[i];
  __syncthreads();
  const int row = blockIdx.x * 8 + threadIdx.x / NCLASS;
  const int col = threadIdx.x % NCLASS;
  if (row >= N_NODES) return;
  const float4* __restrict__ arow4 = (const float4*)&H1[(size_t)row * NHID];
  float acc = 0.f;
#pragma unroll 8
  for (int k4 = 0; k4 < NHID / 4; ++k4) {
    const float4 a = arow4[k4];
    acc = fmaf(a.x, Bs[(k4 * 4 + 0) * NCLASS + col], acc);
    acc = fmaf(a.y, Bs[(k4 * 4 + 1) * NCLASS + col], acc);
    acc = fmaf(a.z, Bs[(k4 * 4 + 2) * NCLASS + col], acc);
    acc = fmaf(a.w, Bs[(k4 * 4 + 3) * NCLASS + col], acc);
  }
  S2b[(size_t)row * NCLASS + col] = f2bf(acc);
}

// ---------------- agg2 + bias + log_softmax fused ----------------
__global__ __launch_bounds__(256) void agg2_lsm_kernel(const int* __restrict__ rp,
                                                       const int2* __restrict__ ent,
                                                       const unsigned short* __restrict__ S2b,
                                                       const float* __restrict__ b2,
                                                       float* __restrict__ out) {
  const int wave = threadIdx.x >> 6;
  const int lane = threadIdx.x & 63;
  const int n = blockIdx.x * 4 + wave;
  if (n >= N_NODES) return;
  const bool act = lane < NCLASS;
  const int cl = act ? lane : 0;
  float acc = act ? b2[cl] : 0.f;
  int e = rp[N_NODES + n];           // graph2 rows are offset by N_NODES
  const int end = rp[N_NODES + n + 1];
  for (; e + 4 <= end; e += 4) {
    const int2 q0 = ent[e], q1 = ent[e + 1], q2 = ent[e + 2], q3 = ent[e + 3];
    const unsigned s0 = S2b[(size_t)q0.x * NCLASS + cl];
    const unsigned s1 = S2b[(size_t)q1.x * NCLASS + cl];
    const unsigned s2 = S2b[(size_t)q2.x * NCLASS + cl];
    const unsigned s3 = S2b[(size_t)q3.x * NCLASS + cl];
    if (act) {
      acc = fmaf(__int_as_float(q0.y), bf_lo(s0), acc);
      acc = fmaf(__int_as_float(q1.y), bf_lo(s1), acc);
      acc = fmaf(__int_as_float(q2.y), bf_lo(s2), acc);
      acc = fmaf(__int_as_float(q3.y), bf_lo(s3), acc);
    }
  }
  for (; e < end; ++e) {
    const int2 q = ent[e];
    const unsigned s = S2b[(size_t)q.x * NCLASS + cl];
    if (act) acc = fmaf(__int_as_float(q.y), bf_lo(s), acc);
  }
  const float v = act ? acc : -3.4e38f;
  float m = v;
#pragma unroll
  for (int off = 32; off; off >>= 1) m = fmaxf(m, __shfl_xor(m, off));
  float ex = act ? __expf(v - m) : 0.f;
  float s = ex;
#pragma unroll
  for (int off = 32; off; off >>= 1) s += __shfl_xor(s, off);
  const float lse = m + __logf(s);
  if (act) out[(size_t)n * NCLASS + lane] = v - lse;
}

extern "C" void kernel_launch(void* const* d_in, const int* in_sizes, int n_in,
                              void* d_out, int out_size, void* d_ws, size_t ws_size,
                              hipStream_t stream) {
  const float* x   = (const float*)d_in[0];
  const int*   ei1 = (const int*)d_in[2];
  const float* ew1 = (const float*)d_in[3];
  const int*   ei2 = (const int*)d_in[4];
  const float* ew2 = (const float*)d_in[5];
  const float* W1  = (const float*)d_in[6];
  const float* b1  = (const float*)d_in[7];
  const float* W2  = (const float*)d_in[8];
  const float* b2  = (const float*)d_in[9];
  float* out = (float*)d_out;

  // workspace layout (~69 MB)
  float*          H1      = (float*)d_ws;                               // 25.6 MB
  int2*           ent     = (int2*)(H1 + (size_t)N_NODES * NHID);       // 25.6 MB
  unsigned short* S1b     = (unsigned short*)(ent + E_TOT);             // 12.8 MB
  unsigned short* S2b     = S1b + (size_t)N_NODES * NHID;               // 4 MB
  int*            row_ptr = (int*)(S2b + (size_t)N_NODES * NCLASS);     // 100001
  int*            cursor  = row_ptr + (N_TOT + 1);                      // 100000
  int*            partials = cursor + N_TOT;                            // 64

  // GEMM1 (independent of CSR build)
  gemm1_kernel<<<(N_NODES + 63) / 64, 256, 0, stream>>>(x, W1, S1b);

  // combined CSR build for both graphs
  zero_i32_kernel<<<(N_TOT + 255) / 256, 256, 0, stream>>>(cursor, N_TOT);
  hist_kernel<<<(E_TOT + 255) / 256, 256, 0, stream>>>(ei1, ei2, cursor);
  scan1_kernel<<<SCAN_NBLK, 256, 0, stream>>>(cursor, row_ptr, partials);
  scan2_kernel<<<1, 64, 0, stream>>>(partials);
  scan3_kernel<<<(N_TOT + 1 + 255) / 256, 256, 0, stream>>>(row_ptr, cursor, partials);
  fill_kernel<<<(E_TOT + 255) / 256, 256, 0, stream>>>(ei1, ew1, ei2, ew2, cursor, ent);

  // layer 1 aggregate (+bias+relu)
  agg1_kernel<<<(N_NODES + 3) / 4, 256, 0, stream>>>(row_ptr, ent, S1b, b1, H1);

  // layer 2
  gemm2_kernel<<<(N_NODES + 7) / 8, 320, 0, stream>>>(H1, W2, S2b);
  agg2_lsm_kernel<<<(N_NODES + 3) / 4, 256, 0, stream>>>(row_ptr, ent, S2b, b2, out);
}

// Round 4
// 294.029 us; speedup vs baseline: 10.5849x; 2.2108x over previous
//
#include <hip/hip_runtime.h>
#include <hip/hip_bf16.h>
#include <math.h>

#define N_NODES 50000
#define N_TOT   100000
#define N_EDGES 1600000
#define E_TOT   3200000
#define NFEAT   512
#define NHID    128
#define NCLASS  40

#define NPB   256                              // nodes per bucket
#define NBUCK ((N_TOT + NPB - 1) / NPB)        // 391
#define BCAP  9216                             // slots per bucket (mean 8192, +11 sigma)

__device__ __forceinline__ float bf_lo(unsigned u) { return __uint_as_float(u << 16); }
__device__ __forceinline__ float bf_hi(unsigned u) { return __uint_as_float(u & 0xFFFF0000u); }
__device__ __forceinline__ unsigned short f2bf(float f) {
  __hip_bfloat16 h = __float2bfloat16(f);
  return *(unsigned short*)&h;
}

typedef __attribute__((ext_vector_type(8))) __bf16 bf16x8;
typedef __attribute__((ext_vector_type(4))) float f32x4;

// ---------------- GEMM1 (MFMA): S1b[50000,128](bf16) = x[M,512] @ W1[512,128] ----------------
// 128x128 block, BK=32, 4 waves (2x2 of 64x64), 16x16x32 bf16 MFMA, fp32 accum.
// LDS rows padded to 80B -> frag reads are 2-way bank aliased (free).
#define APAD 80
__global__ __launch_bounds__(256) void gemm1_kernel(const float* __restrict__ A,
                                                    const float* __restrict__ B,
                                                    unsigned short* __restrict__ Cb) {
  __shared__ unsigned short As[128 * APAD / 2];  // [row][k0..k0+31], padded
  __shared__ unsigned short Bt[128 * APAD / 2];  // [col][k0..k0+31], transposed, padded
  const int tid = threadIdx.x;
  const int lane = tid & 63;
  const int wave = tid >> 6;
  const int wm = wave >> 1, wn = wave & 1;
  const int rowBase = blockIdx.x * 128;

  f32x4 acc[4][4];
#pragma unroll
  for (int i = 0; i < 4; ++i)
#pragma unroll
    for (int j = 0; j < 4; ++j) acc[i][j] = (f32x4){0.f, 0.f, 0.f, 0.f};

  const int kb = (lane >> 4) * 8;   // frag k base (elems)
  const int rA = tid >> 1;          // A stage: row, 2 threads/row
  const int cA = (tid & 1) * 4;     // float4 chunk base
  int garow = rowBase + rA; if (garow > N_NODES - 1) garow = N_NODES - 1;
  const float4* __restrict__ Arow = (const float4*)&A[(size_t)garow * NFEAT];
  const int rB = tid >> 3;          // B stage: k-row, 8 threads/row
  const int cB = tid & 7;

  for (int k0 = 0; k0 < NFEAT; k0 += 32) {
    // stage A tile 128x32 fp32 -> bf16
#pragma unroll
    for (int j = 0; j < 4; ++j) {
      const float4 v = Arow[(k0 >> 2) + cA + j];
      ushort4 o;
      o.x = f2bf(v.x); o.y = f2bf(v.y); o.z = f2bf(v.z); o.w = f2bf(v.w);
      *(ushort4*)((char*)As + rA * APAD + (cA + j) * 8) = o;
    }
    // stage B tile 32x128 fp32 -> bf16 transposed [col][k]
    {
      const float4* __restrict__ Brow = (const float4*)&B[(size_t)(k0 + rB) * NHID];
#pragma unroll
      for (int j = 0; j < 4; ++j) {
        const int c = cB + 8 * j;
        const float4 v = Brow[c];
        const int n0 = c * 4;
        *(unsigned short*)((char*)Bt + (n0 + 0) * APAD + rB * 2) = f2bf(v.x);
        *(unsigned short*)((char*)Bt + (n0 + 1) * APAD + rB * 2) = f2bf(v.y);
        *(unsigned short*)((char*)Bt + (n0 + 2) * APAD + rB * 2) = f2bf(v.z);
        *(unsigned short*)((char*)Bt + (n0 + 3) * APAD + rB * 2) = f2bf(v.w);
      }
    }
    __syncthreads();
    bf16x8 af[4], bfr[4];
#pragma unroll
    for (int i = 0; i < 4; ++i) {
      const int row = wm * 64 + i * 16 + (lane & 15);
      af[i] = *(const bf16x8*)((const char*)As + row * APAD + kb * 2);
    }
#pragma unroll
    for (int j = 0; j < 4; ++j) {
      const int col = wn * 64 + j * 16 + (lane & 15);
      bfr[j] = *(const bf16x8*)((const char*)Bt + col * APAD + kb * 2);
    }
#pragma unroll
    for (int i = 0; i < 4; ++i)
#pragma unroll
      for (int j = 0; j < 4; ++j)
        acc[i][j] = __builtin_amdgcn_mfma_f32_16x16x32_bf16(af[i], bfr[j], acc[i][j], 0, 0, 0);
    __syncthreads();
  }
  // epilogue: C/D layout col=lane&15, row=(lane>>4)*4+q (m89-verified)
#pragma unroll
  for (int i = 0; i < 4; ++i) {
#pragma unroll
    for (int q = 0; q < 4; ++q) {
      const int grow = rowBase + wm * 64 + i * 16 + (lane >> 4) * 4 + q;
      if (grow < N_NODES) {
#pragma unroll
        for (int j = 0; j < 4; ++j) {
          const int col = wn * 64 + j * 16 + (lane & 15);
          Cb[(size_t)grow * NHID + col] = f2bf(acc[i][j][q]);
        }
      }
    }
  }
}

// ---------------- CSR build v2: bucketed, write-localized ----------------
__global__ void init_small_kernel(int* __restrict__ bcur, int* __restrict__ row_ptr) {
  const int t = threadIdx.x;
  if (t < NBUCK) bcur[t] = 0;
  if (t == NBUCK) row_ptr[N_TOT] = E_TOT;
}

// per-WG: 2048 edges, LDS 391-bucket hist, bulk-reserve, direct bucket-window writes
__global__ __launch_bounds__(256) void bucketize_kernel(const int* __restrict__ ei,
                                                        const float* __restrict__ ew,
                                                        const int node_off,
                                                        int* __restrict__ bcur,
                                                        int2* __restrict__ bkt) {
  __shared__ int hist[NBUCK];
  __shared__ int base[NBUCK];
  const int tid = threadIdx.x;
  for (int i = tid; i < NBUCK; i += 256) hist[i] = 0;
  __syncthreads();
  const int e0 = (blockIdx.x * 256 + tid) * 8;
  const bool valid = e0 < N_EDGES;
  int key[8]; float wv[8]; int bb[8]; int rank[8];
  if (valid) {
    const int4 s0 = *(const int4*)&ei[e0];
    const int4 s1 = *(const int4*)&ei[e0 + 4];
    const int4 d0 = *(const int4*)&ei[N_EDGES + e0];
    const int4 d1 = *(const int4*)&ei[N_EDGES + e0 + 4];
    const float4 w0 = *(const float4*)&ew[e0];
    const float4 w1 = *(const float4*)&ew[e0 + 4];
    const int srcs[8] = {s0.x, s0.y, s0.z, s0.w, s1.x, s1.y, s1.z, s1.w};
    const int dsts[8] = {d0.x, d0.y, d0.z, d0.w, d1.x, d1.y, d1.z, d1.w};
    const float ws[8] = {w0.x, w0.y, w0.z, w0.w, w1.x, w1.y, w1.z, w1.w};
#pragma unroll
    for (int j = 0; j < 8; ++j) {
      const int dg = dsts[j] + node_off;
      const int b = dg >> 8;
      bb[j] = b;
      key[j] = srcs[j] | ((dg & 255) << 17);
      wv[j] = ws[j];
      rank[j] = atomicAdd(&hist[b], 1);
    }
  }
  __syncthreads();
  for (int i = tid; i < NBUCK; i += 256) {
    const int c = hist[i];
    base[i] = c ? atomicAdd(&bcur[i], c) : 0;
  }
  __syncthreads();
  if (valid) {
#pragma unroll
    for (int j = 0; j < 8; ++j) {
      const int pos = base[bb[j]] + rank[j];
      if (pos < BCAP)
        bkt[(size_t)bb[j] * BCAP + pos] = make_int2(key[j], __float_as_int(wv[j]));
    }
  }
}

__global__ void bucket_scan_kernel(const int* __restrict__ bcur, int* __restrict__ bptr) {
  if (threadIdx.x == 0) {
    int run = 0;
    for (int b = 0; b < NBUCK; ++b) { bptr[b] = run; run += bcur[b]; }
  }
}

// one WG per bucket: node-hist -> LDS scan -> row_ptr + localized scatter to final CSR
__global__ __launch_bounds__(256) void finalize_kernel(const int2* __restrict__ bkt,
                                                       const int* __restrict__ bcur,
                                                       const int* __restrict__ bptr,
                                                       int* __restrict__ row_ptr,
                                                       int2* __restrict__ ent) {
  __shared__ int hist[NPB];
  __shared__ int scanb[NPB];
  const int b = blockIdx.x;
  const int tid = threadIdx.x;
  const int cnt = bcur[b];
  const int gbase = bptr[b];
  hist[tid] = 0;
  __syncthreads();
  const int2* __restrict__ src = bkt + (size_t)b * BCAP;
  for (int i = tid; i < cnt; i += 256) atomicAdd(&hist[src[i].x >> 17], 1);
  __syncthreads();
  const int v = hist[tid];
  scanb[tid] = v;
  __syncthreads();
  for (int d = 1; d < 256; d <<= 1) {
    const int t = (tid >= d) ? scanb[tid - d] : 0;
    __syncthreads();
    scanb[tid] += t;
    __syncthreads();
  }
  const int excl = scanb[tid] - v;
  const int node = b * NPB + tid;
  if (node < N_TOT) row_ptr[node] = gbase + excl;
  hist[tid] = gbase + excl;  // reuse as global-position cursor
  __syncthreads();
  for (int i = tid; i < cnt; i += 256) {
    const int2 q = src[i];
    const int pos = atomicAdd(&hist[q.x >> 17], 1);
    ent[pos] = make_int2(q.x & 0x1FFFF, q.y);
  }
}

// ---------------- agg1 (pull, bf16 gather): H1 = relu(b1 + sum w*S1b[src]) ----------------
__global__ __launch_bounds__(256) void agg1_kernel(const int* __restrict__ rp,
                                                   const int2* __restrict__ ent,
                                                   const unsigned short* __restrict__ S1b,
                                                   const float* __restrict__ b1,
                                                   float* __restrict__ H1) {
  const int wave = threadIdx.x >> 6;
  const int lane = threadIdx.x & 63;
  const int n = blockIdx.x * 4 + wave;
  if (n >= N_NODES) return;
  const int c = lane << 1;
  float2 acc = *(const float2*)&b1[c];
  int e = rp[n];
  const int end = rp[n + 1];
  for (; e + 4 <= end; e += 4) {
    const int2 q0 = ent[e], q1 = ent[e + 1], q2 = ent[e + 2], q3 = ent[e + 3];
    const unsigned u0 = *(const unsigned*)&S1b[(size_t)q0.x * NHID + c];
    const unsigned u1 = *(const unsigned*)&S1b[(size_t)q1.x * NHID + c];
    const unsigned u2 = *(const unsigned*)&S1b[(size_t)q2.x * NHID + c];
    const unsigned u3 = *(const unsigned*)&S1b[(size_t)q3.x * NHID + c];
    const float w0 = __int_as_float(q0.y), w1 = __int_as_float(q1.y);
    const float w2 = __int_as_float(q2.y), w3 = __int_as_float(q3.y);
    acc.x = fmaf(w0, bf_lo(u0), acc.x); acc.y = fmaf(w0, bf_hi(u0), acc.y);
    acc.x = fmaf(w1, bf_lo(u1), acc.x); acc.y = fmaf(w1, bf_hi(u1), acc.y);
    acc.x = fmaf(w2, bf_lo(u2), acc.x); acc.y = fmaf(w2, bf_hi(u2), acc.y);
    acc.x = fmaf(w3, bf_lo(u3), acc.x); acc.y = fmaf(w3, bf_hi(u3), acc.y);
  }
  for (; e < end; ++e) {
    const int2 q = ent[e];
    const unsigned u = *(const unsigned*)&S1b[(size_t)q.x * NHID + c];
    const float w = __int_as_float(q.y);
    acc.x = fmaf(w, bf_lo(u), acc.x);
    acc.y = fmaf(w, bf_hi(u), acc.y);
  }
  acc.x = fmaxf(acc.x, 0.f);
  acc.y = fmaxf(acc.y, 0.f);
  *(float2*)&H1[(size_t)n * NHID + c] = acc;
}

// ---------------- GEMM2: S2b[M,40](bf16) = H1[M,128] @ W2[128,40] ----------------
__global__ __launch_bounds__(320) void gemm2_kernel(const float* __restrict__ H1,
                                                    const float* __restrict__ W2,
                                                    unsigned short* __restrict__ S2b) {
  __shared__ float Bs[NHID * NCLASS];
  for (int i = threadIdx.x; i < NHID * NCLASS; i += 320) Bs[i] = W2[i];
  __syncthreads();
  const int row = blockIdx.x * 8 + threadIdx.x / NCLASS;
  const int col = threadIdx.x % NCLASS;
  if (row >= N_NODES) return;
  const float4* __restrict__ arow4 = (const float4*)&H1[(size_t)row * NHID];
  float acc = 0.f;
#pragma unroll 8
  for (int k4 = 0; k4 < NHID / 4; ++k4) {
    const float4 a = arow4[k4];
    acc = fmaf(a.x, Bs[(k4 * 4 + 0) * NCLASS + col], acc);
    acc = fmaf(a.y, Bs[(k4 * 4 + 1) * NCLASS + col], acc);
    acc = fmaf(a.z, Bs[(k4 * 4 + 2) * NCLASS + col], acc);
    acc = fmaf(a.w, Bs[(k4 * 4 + 3) * NCLASS + col], acc);
  }
  S2b[(size_t)row * NCLASS + col] = f2bf(acc);
}

// ---------------- agg2 + bias + log_softmax fused ----------------
__global__ __launch_bounds__(256) void agg2_lsm_kernel(const int* __restrict__ rp,
                                                       const int2* __restrict__ ent,
                                                       const unsigned short* __restrict__ S2b,
                                                       const float* __restrict__ b2,
                                                       float* __restrict__ out) {
  const int wave = threadIdx.x >> 6;
  const int lane = threadIdx.x & 63;
  const int n = blockIdx.x * 4 + wave;
  if (n >= N_NODES) return;
  const bool act = lane < NCLASS;
  const int cl = act ? lane : 0;
  float acc = act ? b2[cl] : 0.f;
  int e = rp[N_NODES + n];
  const int end = rp[N_NODES + n + 1];
  for (; e + 4 <= end; e += 4) {
    const int2 q0 = ent[e], q1 = ent[e + 1], q2 = ent[e + 2], q3 = ent[e + 3];
    const unsigned s0 = S2b[(size_t)q0.x * NCLASS + cl];
    const unsigned s1 = S2b[(size_t)q1.x * NCLASS + cl];
    const unsigned s2 = S2b[(size_t)q2.x * NCLASS + cl];
    const unsigned s3 = S2b[(size_t)q3.x * NCLASS + cl];
    if (act) {
      acc = fmaf(__int_as_float(q0.y), bf_lo(s0), acc);
      acc = fmaf(__int_as_float(q1.y), bf_lo(s1), acc);
      acc = fmaf(__int_as_float(q2.y), bf_lo(s2), acc);
      acc = fmaf(__int_as_float(q3.y), bf_lo(s3), acc);
    }
  }
  for (; e < end; ++e) {
    const int2 q = ent[e];
    const unsigned s = S2b[(size_t)q.x * NCLASS + cl];
    if (act) acc = fmaf(__int_as_float(q.y), bf_lo(s), acc);
  }
  const float v = act ? acc : -3.4e38f;
  float m = v;
#pragma unroll
  for (int off = 32; off; off >>= 1) m = fmaxf(m, __shfl_xor(m, off));
  float ex = act ? __expf(v - m) : 0.f;
  float s = ex;
#pragma unroll
  for (int off = 32; off; off >>= 1) s += __shfl_xor(s, off);
  const float lse = m + __logf(s);
  if (act) out[(size_t)n * NCLASS + lane] = v - lse;
}

extern "C" void kernel_launch(void* const* d_in, const int* in_sizes, int n_in,
                              void* d_out, int out_size, void* d_ws, size_t ws_size,
                              hipStream_t stream) {
  const float* x   = (const float*)d_in[0];
  const int*   ei1 = (const int*)d_in[2];
  const float* ew1 = (const float*)d_in[3];
  const int*   ei2 = (const int*)d_in[4];
  const float* ew2 = (const float*)d_in[5];
  const float* W1  = (const float*)d_in[6];
  const float* b1  = (const float*)d_in[7];
  const float* W2  = (const float*)d_in[8];
  const float* b2  = (const float*)d_in[9];
  float* out = (float*)d_out;

  // workspace (~68.4 MB). bkt (28.84 MB) is dead after finalize; H1 (25.6 MB,
  // written by agg1) and S2b (4 MB, written by gemm2) alias its region.
  char* base = (char*)d_ws;
  int2*           bkt     = (int2*)base;                      // [0, 28.84M)
  float*          H1      = (float*)base;                     // [0, 25.6M)  alias
  unsigned short* S2b     = (unsigned short*)(base + 25600000); // [25.6M, 29.6M) alias
  int2*           ent     = (int2*)(base + 29600000);         // 25.6 MB
  unsigned short* S1b     = (unsigned short*)(base + 55200000); // 12.8 MB
  int*            row_ptr = (int*)(base + 68000000);          // (N_TOT+1)*4
  int*            bcur    = (int*)(base + 68400008);          // NBUCK*4
  int*            bptr    = (int*)(base + 68401576);          // NBUCK*4

  // GEMM1 (independent of CSR build)
  gemm1_kernel<<<(N_NODES + 127) / 128, 256, 0, stream>>>(x, W1, S1b);

  // CSR build v2
  init_small_kernel<<<1, 512, 0, stream>>>(bcur, row_ptr);
  bucketize_kernel<<<(N_EDGES / 8 + 255) / 256, 256, 0, stream>>>(ei1, ew1, 0, bcur, bkt);
  bucketize_kernel<<<(N_EDGES / 8 + 255) / 256, 256, 0, stream>>>(ei2, ew2, N_NODES, bcur, bkt);
  bucket_scan_kernel<<<1, 64, 0, stream>>>(bcur, bptr);
  finalize_kernel<<<NBUCK, NPB, 0, stream>>>(bkt, bcur, bptr, row_ptr, ent);

  // layer 1 aggregate (+bias+relu)
  agg1_kernel<<<(N_NODES + 3) / 4, 256, 0, stream>>>(row_ptr, ent, S1b, b1, H1);

  // layer 2
  gemm2_kernel<<<(N_NODES + 7) / 8, 320, 0, stream>>>(H1, W2, S2b);
  agg2_lsm_kernel<<<(N_NODES + 3) / 4, 256, 0, stream>>>(row_ptr, ent, S2b, b2, out);
}

// Round 5
// 269.860 us; speedup vs baseline: 11.5329x; 1.0896x over previous
//
#include <hip/hip_runtime.h>
#include <hip/hip_bf16.h>
#include <math.h>

#define N_NODES 50000
#define N_TOT   100000
#define N_EDGES 1600000
#define E_TOT   3200000
#define NFEAT   512
#define NHID    128
#define NCLASS  40

#define NPB   256                              // nodes per bucket
#define NBUCK ((N_TOT + NPB - 1) / NPB)        // 391
#define BCAP  9216                             // slots per bucket (mean 8192, +11 sigma)

__device__ __forceinline__ float bf_lo(unsigned u) { return __uint_as_float(u << 16); }
__device__ __forceinline__ float bf_hi(unsigned u) { return __uint_as_float(u & 0xFFFF0000u); }
__device__ __forceinline__ unsigned short f2bf(float f) {
  __hip_bfloat16 h = __float2bfloat16(f);
  return *(unsigned short*)&h;
}

typedef __attribute__((ext_vector_type(8))) __bf16 bf16x8;
typedef __attribute__((ext_vector_type(4))) float f32x4;

// ---------------- one-time W1 -> bf16 transposed [col][k] ----------------
__global__ __launch_bounds__(256) void prep_w1_kernel(const float* __restrict__ W1,
                                                      unsigned short* __restrict__ W1bT) {
  const int i = blockIdx.x * 256 + threadIdx.x;  // i = k*128 + col (coalesced read)
  if (i < NFEAT * NHID) {
    const int k = i >> 7, col = i & 127;
    W1bT[col * NFEAT + k] = f2bf(W1[i]);
  }
}

// ---------------- GEMM1 (MFMA): S1b[50000,128](bf16) = x[M,512] @ W1[512,128] ----------------
// 128x128 block, BK=32, 4 waves (2x2 of 64x64), 16x16x32 bf16 MFMA, fp32 accum.
#define APAD 80
#define BPAD 72
__global__ __launch_bounds__(256) void gemm1_kernel(const float* __restrict__ A,
                                                    const unsigned short* __restrict__ W1bT,
                                                    unsigned short* __restrict__ Cb) {
  __shared__ unsigned short As[128 * APAD / 2];  // [row][k], padded 80B rows
  __shared__ unsigned short Bt[128 * BPAD / 2];  // [col][k], padded 72B rows
  const int tid = threadIdx.x;
  const int lane = tid & 63;
  const int wave = tid >> 6;
  const int wm = wave >> 1, wn = wave & 1;
  const int rowBase = blockIdx.x * 128;

  f32x4 acc[4][4];
#pragma unroll
  for (int i = 0; i < 4; ++i)
#pragma unroll
    for (int j = 0; j < 4; ++j) acc[i][j] = (f32x4){0.f, 0.f, 0.f, 0.f};

  const int kb = (lane >> 4) * 8;   // frag k base (elems)
  const int rA = tid >> 1;          // A stage: 2 threads/row
  const int cA = (tid & 1) * 4;     // float4 chunk base
  int garow = rowBase + rA; if (garow > N_NODES - 1) garow = N_NODES - 1;
  const float4* __restrict__ Arow = (const float4*)&A[(size_t)garow * NFEAT];
  const int colB = tid >> 1;        // B stage: 2 threads/col, 32B each
  const int halfB = (tid & 1) * 16; // k-elem offset

  for (int k0 = 0; k0 < NFEAT; k0 += 32) {
    // stage A tile 128x32 fp32 -> bf16
#pragma unroll
    for (int j = 0; j < 4; ++j) {
      const float4 v = Arow[(k0 >> 2) + cA + j];
      ushort4 o;
      o.x = f2bf(v.x); o.y = f2bf(v.y); o.z = f2bf(v.z); o.w = f2bf(v.w);
      *(ushort4*)((char*)As + rA * APAD + (cA + j) * 8) = o;
    }
    // stage B tile: pure bf16 copy from W1bT [col][k] (no convert, no transpose)
    {
      const int4 v0 = *(const int4*)&W1bT[colB * NFEAT + k0 + halfB];
      const int4 v1 = *(const int4*)&W1bT[colB * NFEAT + k0 + halfB + 8];
      *(int4*)((char*)Bt + colB * BPAD + halfB * 2) = v0;
      *(int4*)((char*)Bt + colB * BPAD + halfB * 2 + 16) = v1;
    }
    __syncthreads();
    bf16x8 af[4], bfr[4];
#pragma unroll
    for (int i = 0; i < 4; ++i) {
      const int row = wm * 64 + i * 16 + (lane & 15);
      af[i] = *(const bf16x8*)((const char*)As + row * APAD + kb * 2);
    }
#pragma unroll
    for (int j = 0; j < 4; ++j) {
      const int col = wn * 64 + j * 16 + (lane & 15);
      bfr[j] = *(const bf16x8*)((const char*)Bt + col * BPAD + kb * 2);
    }
#pragma unroll
    for (int i = 0; i < 4; ++i)
#pragma unroll
      for (int j = 0; j < 4; ++j)
        acc[i][j] = __builtin_amdgcn_mfma_f32_16x16x32_bf16(af[i], bfr[j], acc[i][j], 0, 0, 0);
    __syncthreads();
  }
  // epilogue: C/D layout col=lane&15, row=(lane>>4)*4+q
#pragma unroll
  for (int i = 0; i < 4; ++i) {
#pragma unroll
    for (int q = 0; q < 4; ++q) {
      const int grow = rowBase + wm * 64 + i * 16 + (lane >> 4) * 4 + q;
      if (grow < N_NODES) {
#pragma unroll
        for (int j = 0; j < 4; ++j) {
          const int col = wn * 64 + j * 16 + (lane & 15);
          Cb[(size_t)grow * NHID + col] = f2bf(acc[i][j][q]);
        }
      }
    }
  }
}

// ---------------- CSR build: merged bucketize (both graphs), write-localized ----------------
__global__ __launch_bounds__(256) void bucketize_kernel(const int* __restrict__ ei1,
                                                        const float* __restrict__ ew1,
                                                        const int* __restrict__ ei2,
                                                        const float* __restrict__ ew2,
                                                        int* __restrict__ bcur,
                                                        int2* __restrict__ bkt) {
  __shared__ int hist[NBUCK];
  __shared__ int base[NBUCK];
  const int tid = threadIdx.x;
  for (int i = tid; i < NBUCK; i += 256) hist[i] = 0;
  __syncthreads();
  const int e0g = (blockIdx.x * 256 + tid) * 8;
  const bool valid = e0g < E_TOT;
  int key[8]; float wv[8]; int bb[8]; int rank[8];
  if (valid) {
    const int g = (e0g >= N_EDGES);
    const int e0 = e0g - (g ? N_EDGES : 0);
    const int* __restrict__ ei = g ? ei2 : ei1;
    const float* __restrict__ ew = g ? ew2 : ew1;
    const int node_off = g ? N_NODES : 0;
    const int4 s0 = *(const int4*)&ei[e0];
    const int4 s1 = *(const int4*)&ei[e0 + 4];
    const int4 d0 = *(const int4*)&ei[N_EDGES + e0];
    const int4 d1 = *(const int4*)&ei[N_EDGES + e0 + 4];
    const float4 w0 = *(const float4*)&ew[e0];
    const float4 w1 = *(const float4*)&ew[e0 + 4];
    const int srcs[8] = {s0.x, s0.y, s0.z, s0.w, s1.x, s1.y, s1.z, s1.w};
    const int dsts[8] = {d0.x, d0.y, d0.z, d0.w, d1.x, d1.y, d1.z, d1.w};
    const float ws[8] = {w0.x, w0.y, w0.z, w0.w, w1.x, w1.y, w1.z, w1.w};
#pragma unroll
    for (int j = 0; j < 8; ++j) {
      const int dg = dsts[j] + node_off;
      const int b = dg >> 8;
      bb[j] = b;
      key[j] = srcs[j] | ((dg & 255) << 17);
      wv[j] = ws[j];
      rank[j] = atomicAdd(&hist[b], 1);
    }
  }
  __syncthreads();
  for (int i = tid; i < NBUCK; i += 256) {
    const int c = hist[i];
    base[i] = c ? atomicAdd(&bcur[i], c) : 0;
  }
  __syncthreads();
  if (valid) {
#pragma unroll
    for (int j = 0; j < 8; ++j) {
      const int pos = base[bb[j]] + rank[j];
      if (pos < BCAP)
        bkt[(size_t)bb[j] * BCAP + pos] = make_int2(key[j], __float_as_int(wv[j]));
    }
  }
}

// parallel exclusive scan of 391 bucket counts (one block)
__global__ __launch_bounds__(512) void bucket_scan_kernel(const int* __restrict__ bcur,
                                                          int* __restrict__ bptr,
                                                          int* __restrict__ row_ptr) {
  __shared__ int s[512];
  const int tid = threadIdx.x;
  const int v = (tid < NBUCK) ? bcur[tid] : 0;
  s[tid] = v;
  __syncthreads();
  for (int d = 1; d < 512; d <<= 1) {
    const int t = (tid >= d) ? s[tid - d] : 0;
    __syncthreads();
    s[tid] += t;
    __syncthreads();
  }
  if (tid < NBUCK) bptr[tid] = s[tid] - v;
  if (tid == 0) row_ptr[N_TOT] = E_TOT;
}

// one WG per bucket: node-hist -> LDS scan -> row_ptr + localized scatter to final CSR
__global__ __launch_bounds__(256) void finalize_kernel(const int2* __restrict__ bkt,
                                                       const int* __restrict__ bcur,
                                                       const int* __restrict__ bptr,
                                                       int* __restrict__ row_ptr,
                                                       int2* __restrict__ ent) {
  __shared__ int hist[NPB];
  __shared__ int scanb[NPB];
  const int b = blockIdx.x;
  const int tid = threadIdx.x;
  const int cnt = bcur[b];
  const int gbase = bptr[b];
  hist[tid] = 0;
  __syncthreads();
  const int2* __restrict__ src = bkt + (size_t)b * BCAP;
  for (int i = tid; i < cnt; i += 256) atomicAdd(&hist[src[i].x >> 17], 1);
  __syncthreads();
  const int v = hist[tid];
  scanb[tid] = v;
  __syncthreads();
  for (int d = 1; d < 256; d <<= 1) {
    const int t = (tid >= d) ? scanb[tid - d] : 0;
    __syncthreads();
    scanb[tid] += t;
    __syncthreads();
  }
  const int excl = scanb[tid] - v;
  const int node = b * NPB + tid;
  if (node < N_TOT) row_ptr[node] = gbase + excl;
  hist[tid] = gbase + excl;  // reuse as global-position cursor
  __syncthreads();
  for (int i = tid; i < cnt; i += 256) {
    const int2 q = src[i];
    const int pos = atomicAdd(&hist[q.x >> 17], 1);
    ent[pos] = make_int2(q.x & 0x1FFFF, q.y);
  }
}

// ---------------- agg1 (pull, bf16 gather): H1 = relu(b1 + sum w*S1b[src]) ----------------
__global__ __launch_bounds__(256) void agg1_kernel(const int* __restrict__ rp,
                                                   const int2* __restrict__ ent,
                                                   const unsigned short* __restrict__ S1b,
                                                   const float* __restrict__ b1,
                                                   float* __restrict__ H1) {
  const int wave = threadIdx.x >> 6;
  const int lane = threadIdx.x & 63;
  const int n = blockIdx.x * 4 + wave;
  if (n >= N_NODES) return;
  const int c = lane << 1;
  float2 acc = *(const float2*)&b1[c];
  int e = rp[n];
  const int end = rp[n + 1];
  for (; e + 8 <= end; e += 8) {
    int2 q[8]; unsigned u[8];
#pragma unroll
    for (int j = 0; j < 8; ++j) q[j] = ent[e + j];
#pragma unroll
    for (int j = 0; j < 8; ++j) u[j] = *(const unsigned*)&S1b[(size_t)q[j].x * NHID + c];
#pragma unroll
    for (int j = 0; j < 8; ++j) {
      const float w = __int_as_float(q[j].y);
      acc.x = fmaf(w, bf_lo(u[j]), acc.x);
      acc.y = fmaf(w, bf_hi(u[j]), acc.y);
    }
  }
  for (; e < end; ++e) {
    const int2 q = ent[e];
    const unsigned u = *(const unsigned*)&S1b[(size_t)q.x * NHID + c];
    const float w = __int_as_float(q.y);
    acc.x = fmaf(w, bf_lo(u), acc.x);
    acc.y = fmaf(w, bf_hi(u), acc.y);
  }
  acc.x = fmaxf(acc.x, 0.f);
  acc.y = fmaxf(acc.y, 0.f);
  *(float2*)&H1[(size_t)n * NHID + c] = acc;
}

// ---------------- GEMM2: S2b[M,40](bf16) = H1[M,128] @ W2[128,40] ----------------
__global__ __launch_bounds__(320) void gemm2_kernel(const float* __restrict__ H1,
                                                    const float* __restrict__ W2,
                                                    unsigned short* __restrict__ S2b) {
  __shared__ float Bs[NHID * NCLASS];
  for (int i = threadIdx.x; i < NHID * NCLASS; i += 320) Bs[i] = W2[i];
  __syncthreads();
  const int row = blockIdx.x * 8 + threadIdx.x / NCLASS;
  const int col = threadIdx.x % NCLASS;
  if (row >= N_NODES) return;
  const float4* __restrict__ arow4 = (const float4*)&H1[(size_t)row * NHID];
  float acc = 0.f;
#pragma unroll 8
  for (int k4 = 0; k4 < NHID / 4; ++k4) {
    const float4 a = arow4[k4];
    acc = fmaf(a.x, Bs[(k4 * 4 + 0) * NCLASS + col], acc);
    acc = fmaf(a.y, Bs[(k4 * 4 + 1) * NCLASS + col], acc);
    acc = fmaf(a.z, Bs[(k4 * 4 + 2) * NCLASS + col], acc);
    acc = fmaf(a.w, Bs[(k4 * 4 + 3) * NCLASS + col], acc);
  }
  S2b[(size_t)row * NCLASS + col] = f2bf(acc);
}

// ---------------- agg2 + bias + log_softmax fused ----------------
__global__ __launch_bounds__(256) void agg2_lsm_kernel(const int* __restrict__ rp,
                                                       const int2* __restrict__ ent,
                                                       const unsigned short* __restrict__ S2b,
                                                       const float* __restrict__ b2,
                                                       float* __restrict__ out) {
  const int wave = threadIdx.x >> 6;
  const int lane = threadIdx.x & 63;
  const int n = blockIdx.x * 4 + wave;
  if (n >= N_NODES) return;
  const bool act = lane < NCLASS;
  const int cl = act ? lane : 0;
  float acc = act ? b2[cl] : 0.f;
  int e = rp[N_NODES + n];
  const int end = rp[N_NODES + n + 1];
  for (; e + 8 <= end; e += 8) {
    int2 q[8]; unsigned s[8];
#pragma unroll
    for (int j = 0; j < 8; ++j) q[j] = ent[e + j];
#pragma unroll
    for (int j = 0; j < 8; ++j) s[j] = S2b[(size_t)q[j].x * NCLASS + cl];
    if (act) {
#pragma unroll
      for (int j = 0; j < 8; ++j) acc = fmaf(__int_as_float(q[j].y), bf_lo(s[j]), acc);
    }
  }
  for (; e < end; ++e) {
    const int2 q = ent[e];
    const unsigned s = S2b[(size_t)q.x * NCLASS + cl];
    if (act) acc = fmaf(__int_as_float(q.y), bf_lo(s), acc);
  }
  const float v = act ? acc : -3.4e38f;
  float m = v;
#pragma unroll
  for (int off = 32; off; off >>= 1) m = fmaxf(m, __shfl_xor(m, off));
  float ex = act ? __expf(v - m) : 0.f;
  float s = ex;
#pragma unroll
  for (int off = 32; off; off >>= 1) s += __shfl_xor(s, off);
  const float lse = m + __logf(s);
  if (act) out[(size_t)n * NCLASS + lane] = v - lse;
}

extern "C" void kernel_launch(void* const* d_in, const int* in_sizes, int n_in,
                              void* d_out, int out_size, void* d_ws, size_t ws_size,
                              hipStream_t stream) {
  const float* x   = (const float*)d_in[0];
  const int*   ei1 = (const int*)d_in[2];
  const float* ew1 = (const float*)d_in[3];
  const int*   ei2 = (const int*)d_in[4];
  const float* ew2 = (const float*)d_in[5];
  const float* W1  = (const float*)d_in[6];
  const float* b1  = (const float*)d_in[7];
  const float* W2  = (const float*)d_in[8];
  const float* b2  = (const float*)d_in[9];
  float* out = (float*)d_out;

  // workspace (~68.4 MB). bkt dead after finalize; H1/S2b alias it.
  // W1bT lives inside the ent region (gemm1 consumes it before finalize writes ent).
  char* base = (char*)d_ws;
  int2*           bkt     = (int2*)base;                        // [0, 28.84M)
  float*          H1      = (float*)base;                       // [0, 25.6M)  alias
  unsigned short* S2b     = (unsigned short*)(base + 25600000); // [25.6M, 29.6M) alias
  int2*           ent     = (int2*)(base + 29600000);           // [29.6M, 55.2M)
  unsigned short* W1bT    = (unsigned short*)(base + 54000000); // 128KB, inside ent (dead after gemm1)
  unsigned short* S1b     = (unsigned short*)(base + 55200000); // 12.8 MB
  int*            row_ptr = (int*)(base + 68000000);            // (N_TOT+1)*4
  int*            bcur    = (int*)(base + 68400008);            // NBUCK*4
  int*            bptr    = (int*)(base + 68401576);            // NBUCK*4

  // GEMM1 (B pre-converted once; bf16 copy-only staging)
  prep_w1_kernel<<<(NFEAT * NHID + 255) / 256, 256, 0, stream>>>(W1, W1bT);
  gemm1_kernel<<<(N_NODES + 127) / 128, 256, 0, stream>>>(x, W1bT, S1b);

  // CSR build (both graphs in one pass)
  hipMemsetAsync(bcur, 0, NBUCK * sizeof(int), stream);
  bucketize_kernel<<<(E_TOT / 8 + 255) / 256, 256, 0, stream>>>(ei1, ew1, ei2, ew2, bcur, bkt);
  bucket_scan_kernel<<<1, 512, 0, stream>>>(bcur, bptr, row_ptr);
  finalize_kernel<<<NBUCK, NPB, 0, stream>>>(bkt, bcur, bptr, row_ptr, ent);

  // layer 1 aggregate (+bias+relu)
  agg1_kernel<<<(N_NODES + 3) / 4, 256, 0, stream>>>(row_ptr, ent, S1b, b1, H1);

  // layer 2
  gemm2_kernel<<<(N_NODES + 7) / 8, 320, 0, stream>>>(H1, W2, S2b);
  agg2_lsm_kernel<<<(N_NODES + 3) / 4, 256, 0, stream>>>(row_ptr, ent, S2b, b2, out);
}

// Round 6
// 237.412 us; speedup vs baseline: 13.1092x; 1.1367x over previous
//
#include <hip/hip_runtime.h>
#include <hip/hip_bf16.h>
#include <math.h>

#define N_NODES 50000
#define N_TOT   100000
#define N_EDGES 1600000
#define E_TOT   3200000
#define NFEAT   512
#define NHID    128
#define NCLASS  40

#define NPB   256                              // nodes per bucket
#define NBUCK ((N_TOT + NPB - 1) / NPB)        // 391
#define BCAP  9216                             // slots per bucket (mean 8192, +11 sigma)

__device__ __forceinline__ float bf_lo(unsigned u) { return __uint_as_float(u << 16); }
__device__ __forceinline__ float bf_hi(unsigned u) { return __uint_as_float(u & 0xFFFF0000u); }
__device__ __forceinline__ unsigned short f2bf(float f) {
  __hip_bfloat16 h = __float2bfloat16(f);
  return *(unsigned short*)&h;
}
__device__ __forceinline__ unsigned short f2h_bits(float f) {
  const _Float16 h = (_Float16)f;
  return __builtin_bit_cast(unsigned short, h);
}
__device__ __forceinline__ float h2f_bits(unsigned short u) {
  const _Float16 h = __builtin_bit_cast(_Float16, u);
  return (float)h;
}

typedef __attribute__((ext_vector_type(8))) __bf16 bf16x8;
typedef __attribute__((ext_vector_type(4))) float f32x4;

// ---------------- one-time W1 -> bf16 transposed [col][k] ----------------
__global__ __launch_bounds__(256) void prep_w1_kernel(const float* __restrict__ W1,
                                                      unsigned short* __restrict__ W1bT) {
  const int i = blockIdx.x * 256 + threadIdx.x;  // i = k*128 + col (coalesced read)
  if (i < NFEAT * NHID) {
    const int k = i >> 7, col = i & 127;
    W1bT[col * NFEAT + k] = f2bf(W1[i]);
  }
}

// ---------------- GEMM1 (MFMA): S1b slabs [4][N][32](bf16) = x[M,512] @ W1[512,128] ----------------
// 128x128 block, BK=32, 4 waves (2x2 of 64x64), 16x16x32 bf16 MFMA, fp32 accum.
// Output written as 4 column-slabs of 32 cols (3.2MB each) for XCD-sliced agg1.
#define APAD 80
#define BPAD 72
__global__ __launch_bounds__(256) void gemm1_kernel(const float* __restrict__ A,
                                                    const unsigned short* __restrict__ W1bT,
                                                    unsigned short* __restrict__ Cb) {
  __shared__ unsigned short As[128 * APAD / 2];  // [row][k], padded 80B rows
  __shared__ unsigned short Bt[128 * BPAD / 2];  // [col][k], padded 72B rows
  const int tid = threadIdx.x;
  const int lane = tid & 63;
  const int wave = tid >> 6;
  const int wm = wave >> 1, wn = wave & 1;
  const int rowBase = blockIdx.x * 128;

  f32x4 acc[4][4];
#pragma unroll
  for (int i = 0; i < 4; ++i)
#pragma unroll
    for (int j = 0; j < 4; ++j) acc[i][j] = (f32x4){0.f, 0.f, 0.f, 0.f};

  const int kb = (lane >> 4) * 8;   // frag k base (elems)
  const int rA = tid >> 1;          // A stage: 2 threads/row
  const int cA = (tid & 1) * 4;     // float4 chunk base
  int garow = rowBase + rA; if (garow > N_NODES - 1) garow = N_NODES - 1;
  const float4* __restrict__ Arow = (const float4*)&A[(size_t)garow * NFEAT];
  const int colB = tid >> 1;        // B stage: 2 threads/col, 32B each
  const int halfB = (tid & 1) * 16; // k-elem offset

  for (int k0 = 0; k0 < NFEAT; k0 += 32) {
    // stage A tile 128x32 fp32 -> bf16
#pragma unroll
    for (int j = 0; j < 4; ++j) {
      const float4 v = Arow[(k0 >> 2) + cA + j];
      ushort4 o;
      o.x = f2bf(v.x); o.y = f2bf(v.y); o.z = f2bf(v.z); o.w = f2bf(v.w);
      *(ushort4*)((char*)As + rA * APAD + (cA + j) * 8) = o;
    }
    // stage B tile: pure bf16 copy from W1bT [col][k]
    {
      const int4 v0 = *(const int4*)&W1bT[colB * NFEAT + k0 + halfB];
      const int4 v1 = *(const int4*)&W1bT[colB * NFEAT + k0 + halfB + 8];
      *(int4*)((char*)Bt + colB * BPAD + halfB * 2) = v0;
      *(int4*)((char*)Bt + colB * BPAD + halfB * 2 + 16) = v1;
    }
    __syncthreads();
    bf16x8 af[4], bfr[4];
#pragma unroll
    for (int i = 0; i < 4; ++i) {
      const int row = wm * 64 + i * 16 + (lane & 15);
      af[i] = *(const bf16x8*)((const char*)As + row * APAD + kb * 2);
    }
#pragma unroll
    for (int j = 0; j < 4; ++j) {
      const int col = wn * 64 + j * 16 + (lane & 15);
      bfr[j] = *(const bf16x8*)((const char*)Bt + col * BPAD + kb * 2);
    }
#pragma unroll
    for (int i = 0; i < 4; ++i)
#pragma unroll
      for (int j = 0; j < 4; ++j)
        acc[i][j] = __builtin_amdgcn_mfma_f32_16x16x32_bf16(af[i], bfr[j], acc[i][j], 0, 0, 0);
    __syncthreads();
  }
  // epilogue -> slabbed layout: slab = col>>5, Cb[(slab*N + row)*32 + (col&31)]
#pragma unroll
  for (int i = 0; i < 4; ++i) {
#pragma unroll
    for (int q = 0; q < 4; ++q) {
      const int grow = rowBase + wm * 64 + i * 16 + (lane >> 4) * 4 + q;
      if (grow < N_NODES) {
#pragma unroll
        for (int j = 0; j < 4; ++j) {
          const int col = wn * 64 + j * 16 + (lane & 15);
          Cb[((size_t)(col >> 5) * N_NODES + grow) * 32 + (col & 31)] = f2bf(acc[i][j][q]);
        }
      }
    }
  }
}

// ---------------- tiny zero for bucket cursors (replaces 58us rocclr fill) ----------------
__global__ void zero_bcur_kernel(int* __restrict__ bcur) {
  const int t = threadIdx.x;
  if (t < NBUCK) bcur[t] = 0;
}

// ---------------- CSR build: merged bucketize (both graphs), 1024 thr/WG ----------------
__global__ __launch_bounds__(1024) void bucketize_kernel(const int* __restrict__ ei1,
                                                         const float* __restrict__ ew1,
                                                         const int* __restrict__ ei2,
                                                         const float* __restrict__ ew2,
                                                         int* __restrict__ bcur,
                                                         int2* __restrict__ bkt) {
  __shared__ int hist[NBUCK];
  __shared__ int base[NBUCK];
  const int tid = threadIdx.x;
  if (tid < NBUCK) hist[tid] = 0;
  __syncthreads();
  const int e0g = (blockIdx.x * 1024 + tid) * 8;
  const bool valid = e0g < E_TOT;
  int key[8]; float wv[8]; int bb[8]; int rank[8];
  if (valid) {
    const int g = (e0g >= N_EDGES);
    const int e0 = e0g - (g ? N_EDGES : 0);
    const int* __restrict__ ei = g ? ei2 : ei1;
    const float* __restrict__ ew = g ? ew2 : ew1;
    const int node_off = g ? N_NODES : 0;
    const int4 s0 = *(const int4*)&ei[e0];
    const int4 s1 = *(const int4*)&ei[e0 + 4];
    const int4 d0 = *(const int4*)&ei[N_EDGES + e0];
    const int4 d1 = *(const int4*)&ei[N_EDGES + e0 + 4];
    const float4 w0 = *(const float4*)&ew[e0];
    const float4 w1 = *(const float4*)&ew[e0 + 4];
    const int srcs[8] = {s0.x, s0.y, s0.z, s0.w, s1.x, s1.y, s1.z, s1.w};
    const int dsts[8] = {d0.x, d0.y, d0.z, d0.w, d1.x, d1.y, d1.z, d1.w};
    const float ws[8] = {w0.x, w0.y, w0.z, w0.w, w1.x, w1.y, w1.z, w1.w};
#pragma unroll
    for (int j = 0; j < 8; ++j) {
      const int dg = dsts[j] + node_off;
      const int b = dg >> 8;
      bb[j] = b;
      key[j] = srcs[j] | ((dg & 255) << 16);   // src:16 | dstloc:8
      wv[j] = ws[j];
      rank[j] = atomicAdd(&hist[b], 1);
    }
  }
  __syncthreads();
  if (tid < NBUCK) {
    const int c = hist[tid];
    base[tid] = c ? atomicAdd(&bcur[tid], c) : 0;
  }
  __syncthreads();
  if (valid) {
#pragma unroll
    for (int j = 0; j < 8; ++j) {
      const int pos = base[bb[j]] + rank[j];
      if (pos < BCAP)
        bkt[(size_t)bb[j] * BCAP + pos] = make_int2(key[j], __float_as_int(wv[j]));
    }
  }
}

// parallel exclusive scan of 391 bucket counts (one block)
__global__ __launch_bounds__(512) void bucket_scan_kernel(const int* __restrict__ bcur,
                                                          int* __restrict__ bptr,
                                                          int* __restrict__ row_ptr) {
  __shared__ int s[512];
  const int tid = threadIdx.x;
  const int v = (tid < NBUCK) ? bcur[tid] : 0;
  s[tid] = v;
  __syncthreads();
  for (int d = 1; d < 512; d <<= 1) {
    const int t = (tid >= d) ? s[tid - d] : 0;
    __syncthreads();
    s[tid] += t;
    __syncthreads();
  }
  if (tid < NBUCK) bptr[tid] = s[tid] - v;
  if (tid == 0) row_ptr[N_TOT] = E_TOT;
}

// one WG per bucket: node-hist -> LDS scan -> row_ptr + packed 4B CSR entries
__global__ __launch_bounds__(256) void finalize_kernel(const int2* __restrict__ bkt,
                                                       const int* __restrict__ bcur,
                                                       const int* __restrict__ bptr,
                                                       int* __restrict__ row_ptr,
                                                       unsigned* __restrict__ ent) {
  __shared__ int hist[NPB];
  __shared__ int scanb[NPB];
  const int b = blockIdx.x;
  const int tid = threadIdx.x;
  const int cnt = bcur[b];
  const int gbase = bptr[b];
  hist[tid] = 0;
  __syncthreads();
  const int2* __restrict__ src = bkt + (size_t)b * BCAP;
  for (int i = tid; i < cnt; i += 256) atomicAdd(&hist[src[i].x >> 16], 1);
  __syncthreads();
  const int v = hist[tid];
  scanb[tid] = v;
  __syncthreads();
  for (int d = 1; d < 256; d <<= 1) {
    const int t = (tid >= d) ? scanb[tid - d] : 0;
    __syncthreads();
    scanb[tid] += t;
    __syncthreads();
  }
  const int excl = scanb[tid] - v;
  const int node = b * NPB + tid;
  if (node < N_TOT) row_ptr[node] = gbase + excl;
  hist[tid] = gbase + excl;  // reuse as global-position cursor
  __syncthreads();
  for (int i = tid; i < cnt; i += 256) {
    const int2 q = src[i];
    const int pos = atomicAdd(&hist[q.x >> 16], 1);
    ent[pos] = (unsigned)(q.x & 0xFFFF) | ((unsigned)f2h_bits(__int_as_float(q.y)) << 16);
  }
}

// ---------------- agg1 (pull, XCD-sliced): H1 = relu(b1 + sum w*S1b[src]) ----------------
// block b: col-group g=b&3 (32 cols, slab g); wave = 4 nodes x 16 lanes x float2.
__global__ __launch_bounds__(256) void agg1_kernel(const int* __restrict__ rp,
                                                   const unsigned* __restrict__ ent,
                                                   const unsigned short* __restrict__ S1b,
                                                   const float* __restrict__ b1,
                                                   float* __restrict__ H1) {
  const int tid = threadIdx.x;
  const int wave = tid >> 6, lane = tid & 63;
  const int sub = lane >> 4, l = lane & 15;
  const int g = blockIdx.x & 3;
  const int n = (blockIdx.x >> 2) * 16 + wave * 4 + sub;
  if (n >= N_NODES) return;
  const int c = l << 1;
  const unsigned short* __restrict__ slab = S1b + (size_t)g * N_NODES * 32;
  float2 acc = *(const float2*)&b1[g * 32 + c];
  int e = rp[n];
  const int end = rp[n + 1];
  for (; e + 4 <= end; e += 4) {
    const unsigned p0 = ent[e], p1 = ent[e + 1], p2 = ent[e + 2], p3 = ent[e + 3];
    const unsigned u0 = *(const unsigned*)&slab[(size_t)(p0 & 0xFFFF) * 32 + c];
    const unsigned u1 = *(const unsigned*)&slab[(size_t)(p1 & 0xFFFF) * 32 + c];
    const unsigned u2 = *(const unsigned*)&slab[(size_t)(p2 & 0xFFFF) * 32 + c];
    const unsigned u3 = *(const unsigned*)&slab[(size_t)(p3 & 0xFFFF) * 32 + c];
    const float w0 = h2f_bits(p0 >> 16), w1 = h2f_bits(p1 >> 16);
    const float w2 = h2f_bits(p2 >> 16), w3 = h2f_bits(p3 >> 16);
    acc.x = fmaf(w0, bf_lo(u0), acc.x); acc.y = fmaf(w0, bf_hi(u0), acc.y);
    acc.x = fmaf(w1, bf_lo(u1), acc.x); acc.y = fmaf(w1, bf_hi(u1), acc.y);
    acc.x = fmaf(w2, bf_lo(u2), acc.x); acc.y = fmaf(w2, bf_hi(u2), acc.y);
    acc.x = fmaf(w3, bf_lo(u3), acc.x); acc.y = fmaf(w3, bf_hi(u3), acc.y);
  }
  for (; e < end; ++e) {
    const unsigned p = ent[e];
    const unsigned u = *(const unsigned*)&slab[(size_t)(p & 0xFFFF) * 32 + c];
    const float w = h2f_bits(p >> 16);
    acc.x = fmaf(w, bf_lo(u), acc.x);
    acc.y = fmaf(w, bf_hi(u), acc.y);
  }
  acc.x = fmaxf(acc.x, 0.f);
  acc.y = fmaxf(acc.y, 0.f);
  *(float2*)&H1[(size_t)n * NHID + g * 32 + c] = acc;
}

// ---------------- GEMM2: S2b[M,40](bf16) = H1[M,128] @ W2[128,40] ----------------
__global__ __launch_bounds__(320) void gemm2_kernel(const float* __restrict__ H1,
                                                    const float* __restrict__ W2,
                                                    unsigned short* __restrict__ S2b) {
  __shared__ float Bs[NHID * NCLASS];
  for (int i = threadIdx.x; i < NHID * NCLASS; i += 320) Bs[i] = W2[i];
  __syncthreads();
  const int row = blockIdx.x * 8 + threadIdx.x / NCLASS;
  const int col = threadIdx.x % NCLASS;
  if (row >= N_NODES) return;
  const float4* __restrict__ arow4 = (const float4*)&H1[(size_t)row * NHID];
  float acc = 0.f;
#pragma unroll 8
  for (int k4 = 0; k4 < NHID / 4; ++k4) {
    const float4 a = arow4[k4];
    acc = fmaf(a.x, Bs[(k4 * 4 + 0) * NCLASS + col], acc);
    acc = fmaf(a.y, Bs[(k4 * 4 + 1) * NCLASS + col], acc);
    acc = fmaf(a.z, Bs[(k4 * 4 + 2) * NCLASS + col], acc);
    acc = fmaf(a.w, Bs[(k4 * 4 + 3) * NCLASS + col], acc);
  }
  S2b[(size_t)row * NCLASS + col] = f2bf(acc);
}

// ---------------- agg2 + bias + log_softmax fused ----------------
__global__ __launch_bounds__(256) void agg2_lsm_kernel(const int* __restrict__ rp,
                                                       const unsigned* __restrict__ ent,
                                                       const unsigned short* __restrict__ S2b,
                                                       const float* __restrict__ b2,
                                                       float* __restrict__ out) {
  const int wave = threadIdx.x >> 6;
  const int lane = threadIdx.x & 63;
  const int n = blockIdx.x * 4 + wave;
  if (n >= N_NODES) return;
  const bool act = lane < NCLASS;
  const int cl = act ? lane : 0;
  float acc = act ? b2[cl] : 0.f;
  int e = rp[N_NODES + n];
  const int end = rp[N_NODES + n + 1];
  for (; e + 8 <= end; e += 8) {
    unsigned p[8]; unsigned s[8];
#pragma unroll
    for (int j = 0; j < 8; ++j) p[j] = ent[e + j];
#pragma unroll
    for (int j = 0; j < 8; ++j) s[j] = S2b[(size_t)(p[j] & 0xFFFF) * NCLASS + cl];
    if (act) {
#pragma unroll
      for (int j = 0; j < 8; ++j) acc = fmaf(h2f_bits(p[j] >> 16), bf_lo(s[j]), acc);
    }
  }
  for (; e < end; ++e) {
    const unsigned p = ent[e];
    const unsigned s = S2b[(size_t)(p & 0xFFFF) * NCLASS + cl];
    if (act) acc = fmaf(h2f_bits(p >> 16), bf_lo(s), acc);
  }
  const float v = act ? acc : -3.4e38f;
  float m = v;
#pragma unroll
  for (int off = 32; off; off >>= 1) m = fmaxf(m, __shfl_xor(m, off));
  float ex = act ? __expf(v - m) : 0.f;
  float s = ex;
#pragma unroll
  for (int off = 32; off; off >>= 1) s += __shfl_xor(s, off);
  const float lse = m + __logf(s);
  if (act) out[(size_t)n * NCLASS + lane] = v - lse;
}

extern "C" void kernel_launch(void* const* d_in, const int* in_sizes, int n_in,
                              void* d_out, int out_size, void* d_ws, size_t ws_size,
                              hipStream_t stream) {
  const float* x   = (const float*)d_in[0];
  const int*   ei1 = (const int*)d_in[2];
  const float* ew1 = (const float*)d_in[3];
  const int*   ei2 = (const int*)d_in[4];
  const float* ew2 = (const float*)d_in[5];
  const float* W1  = (const float*)d_in[6];
  const float* b1  = (const float*)d_in[7];
  const float* W2  = (const float*)d_in[8];
  const float* b2  = (const float*)d_in[9];
  float* out = (float*)d_out;

  // workspace (~55.7 MB). bkt dead after finalize; H1/S2b alias it.
  char* base = (char*)d_ws;
  int2*           bkt     = (int2*)base;                        // [0, 28.83M)
  float*          H1      = (float*)base;                       // [0, 25.6M)  alias (after finalize)
  unsigned short* S2b     = (unsigned short*)(base + 25600000); // [25.6M, 29.6M) alias (after finalize)
  unsigned*       ent     = (unsigned*)(base + 29600000);       // [29.6M, 42.4M) packed {src16,w-fp16}
  unsigned short* W1bT    = (unsigned short*)(base + 42400000); // 128KB (dead after gemm1)
  unsigned short* S1b     = (unsigned short*)(base + 42531072); // 12.8MB, 4 slabs [g][N][32]
  int*            row_ptr = (int*)(base + 55331072);            // (N_TOT+1)*4
  int*            bcur    = (int*)(base + 55731076);            // NBUCK*4
  int*            bptr    = (int*)(base + 55732640);            // NBUCK*4

  // GEMM1 (B pre-converted once; bf16 copy-only staging; slabbed output)
  prep_w1_kernel<<<(NFEAT * NHID + 255) / 256, 256, 0, stream>>>(W1, W1bT);
  gemm1_kernel<<<(N_NODES + 127) / 128, 256, 0, stream>>>(x, W1bT, S1b);

  // CSR build (both graphs in one pass)
  zero_bcur_kernel<<<1, 512, 0, stream>>>(bcur);
  bucketize_kernel<<<(E_TOT / 8 + 1023) / 1024, 1024, 0, stream>>>(ei1, ew1, ei2, ew2, bcur, bkt);
  bucket_scan_kernel<<<1, 512, 0, stream>>>(bcur, bptr, row_ptr);
  finalize_kernel<<<NBUCK, NPB, 0, stream>>>(bkt, bcur, bptr, row_ptr, ent);

  // layer 1 aggregate (+bias+relu), XCD-sliced by col-group
  agg1_kernel<<<4 * ((N_NODES + 15) / 16), 256, 0, stream>>>(row_ptr, ent, S1b, b1, H1);

  // layer 2
  gemm2_kernel<<<(N_NODES + 7) / 8, 320, 0, stream>>>(H1, W2, S2b);
  agg2_lsm_kernel<<<(N_NODES + 3) / 4, 256, 0, stream>>>(row_ptr, ent, S2b, b2, out);
}